// Round 1
// baseline (120.181 us; speedup 1.0000x reference)
//
#include <hip/hip_runtime.h>

#define HID 64
#define VOC 64
#define NSLOT 8
#define NB 256
#define SEQL 2048

// ---------------------------------------------------------------------------
// Kernel 1: per-vocab precompute (single block, 256 threads).
// Computes, for each vocab id v in [0,64):
//   h_v  : LN(embed[v] + FFN(embed[v]))          [64]
//   score_v = h_v . gate_w + gate_b
//   q_v  = h_v @ q_w + q_b                        [64]
//   G[v][u] = (h_v . q_u) / sqrt(H)               (slot-id v, last-token-id u)
//   O[v][:] = h_v @ out_w                         [64]
//   order[] = vocab ids sorted by score desc (ties: lower id first)
// ---------------------------------------------------------------------------
__global__ __launch_bounds__(256) void precompute_kernel(
    const float* __restrict__ embed, const float* __restrict__ w1, const float* __restrict__ b1,
    const float* __restrict__ w2, const float* __restrict__ b2,
    const float* __restrict__ ln_g, const float* __restrict__ ln_b,
    const float* __restrict__ gate_w, const float* __restrict__ gate_b,
    const float* __restrict__ q_w, const float* __restrict__ q_b,
    const float* __restrict__ out_w,
    float* __restrict__ wsG, float* __restrict__ wsO, int* __restrict__ wsOrder)
{
    __shared__ float ff1[VOC * 2 * HID];   // 32 KB; reused as q_v after phase B
    __shared__ float hsm[VOC * HID];       // 16 KB; z then h in place
    __shared__ float score[VOC];
    const int t = threadIdx.x;

    // Phase A: ff1[v][j] = relu(embed[v] . w1[:,j] + b1[j]),  j in [0,128)
    for (int p = t; p < VOC * 2 * HID; p += 256) {
        const int v = p >> 7, j = p & 127;
        float acc = b1[j];
        const float* e = embed + v * HID;
#pragma unroll 16
        for (int i = 0; i < HID; ++i) acc = fmaf(e[i], w1[i * 2 * HID + j], acc);
        ff1[p] = fmaxf(acc, 0.0f);
    }
    __syncthreads();

    // Phase B: z[v][i] = embed[v][i] + ff1[v] . w2[:,i] + b2[i]
    for (int p = t; p < VOC * HID; p += 256) {
        const int v = p >> 6, i = p & 63;
        float acc = b2[i];
#pragma unroll 16
        for (int j = 0; j < 2 * HID; ++j) acc = fmaf(ff1[v * 2 * HID + j], w2[j * HID + i], acc);
        hsm[p] = acc + embed[p];
    }
    __syncthreads();

    // Phase C: LayerNorm per v + gate score (64 lanes, one v each)
    if (t < VOC) {
        const int v = t;
        float mu = 0.0f;
        for (int i = 0; i < HID; ++i) mu += hsm[v * HID + i];
        mu *= (1.0f / HID);
        float var = 0.0f;
        for (int i = 0; i < HID; ++i) { const float d = hsm[v * HID + i] - mu; var = fmaf(d, d, var); }
        var *= (1.0f / HID);
        const float inv = 1.0f / sqrtf(var + 1e-5f);
        float sc = gate_b[0];
        for (int i = 0; i < HID; ++i) {
            const float hv = (hsm[v * HID + i] - mu) * inv * ln_g[i] + ln_b[i];
            hsm[v * HID + i] = hv;
            sc = fmaf(hv, gate_w[i], sc);
        }
        score[v] = sc;
    }
    __syncthreads();

    // Phase D: q_v[u][i] = h_u . q_w[:,i] + q_b[i]   (into ff1 storage)
    float* qv = ff1;
    for (int p = t; p < VOC * HID; p += 256) {
        const int u = p >> 6, i = p & 63;
        float acc = q_b[i];
#pragma unroll 16
        for (int k = 0; k < HID; ++k) acc = fmaf(hsm[u * HID + k], q_w[k * HID + i], acc);
        qv[p] = acc;
    }
    __syncthreads();

    // Phase E: G[v][u] = (h_v . q_u) / 8 ;  O[v][o] = h_v . out_w[:,o]
    for (int p = t; p < VOC * VOC; p += 256) {
        const int v = p >> 6, u = p & 63;
        float acc = 0.0f;
#pragma unroll 16
        for (int i = 0; i < HID; ++i) acc = fmaf(hsm[v * HID + i], qv[u * HID + i], acc);
        wsG[p] = acc * 0.125f;   // 1/sqrt(64)
    }
    for (int p = t; p < VOC * VOC; p += 256) {
        const int v = p >> 6, o = p & 63;
        float acc = 0.0f;
#pragma unroll 16
        for (int i = 0; i < HID; ++i) acc = fmaf(hsm[v * HID + i], out_w[i * VOC + o], acc);
        wsO[p] = acc;
    }
    // Phase F: rank vocab ids by score desc, tie -> lower id first
    if (t < VOC) {
        const float sv = score[t];
        int r = 0;
        for (int u = 0; u < VOC; ++u) {
            const float su = score[u];
            if (su > sv || (su == sv && u < t)) ++r;
        }
        wsOrder[r] = t;
    }
}

// ---------------------------------------------------------------------------
// Kernel 2: one block per batch row. Histogram of vocab ids -> greedy top-8
// multiset -> tiny softmax/entropy gate -> logits via precomputed O.
// ---------------------------------------------------------------------------
__global__ __launch_bounds__(256) void batch_kernel(
    const int* __restrict__ seq, const float* __restrict__ out_b,
    const float* __restrict__ wsG, const float* __restrict__ wsO,
    const int* __restrict__ wsOrder,
    float* __restrict__ ent_ws, float* __restrict__ out)
{
    __shared__ int hist[VOC];
    __shared__ int vids[NSLOT];
    __shared__ float eff[NSLOT];
    const int t = threadIdx.x;
    const int b = blockIdx.x;

    if (t < VOC) hist[t] = 0;
    __syncthreads();

    const int4* row4 = (const int4*)(seq + (size_t)b * SEQL);
    for (int p = t; p < SEQL / 4; p += 256) {
        const int4 v = row4[p];
        atomicAdd(&hist[v.x], 1);
        atomicAdd(&hist[v.y], 1);
        atomicAdd(&hist[v.z], 1);
        atomicAdd(&hist[v.w], 1);
    }
    __syncthreads();

    if (t == 0) {
        // Greedy: walk ids in descending-score order, take with multiplicity.
        int r = NSLOT, n = 0, pos = 0;
        while (r > 0) {
            const int v = wsOrder[pos++];
            int c = hist[v];
            if (c > r) c = r;
            for (int k = 0; k < c; ++k) vids[n++] = v;
            r -= c;
        }
        const int vlast = seq[(size_t)b * SEQL + (SEQL - 1)];
        float la[NSLOT], m = -1e30f;
        for (int k = 0; k < NSLOT; ++k) {
            la[k] = wsG[vids[k] * VOC + vlast];
            m = fmaxf(m, la[k]);
        }
        float e[NSLOT], s = 0.0f;
        for (int k = 0; k < NSLOT; ++k) { e[k] = expf(la[k] - m); s += e[k]; }
        const float invs = 1.0f / s;
        float ent = 0.0f, a[NSLOT];
        for (int k = 0; k < NSLOT; ++k) {
            a[k] = e[k] * invs;
            ent -= a[k] * logf(a[k] + 1e-9f);
        }
        const float high = (ent > 1.5f) ? 1.0f : 0.0f;
        for (int k = 0; k < NSLOT; ++k)
            eff[k] = (1.0f - high) * a[k] + high * (1.0f / NSLOT);
        ent_ws[b] = ent;
    }
    __syncthreads();

    if (t < VOC) {
        float acc = out_b[t];
        for (int k = 0; k < NSLOT; ++k)
            acc = fmaf(eff[k], wsO[vids[k] * VOC + t], acc);
        out[(size_t)b * VOC + t] = acc;
    }
}

// ---------------------------------------------------------------------------
// Kernel 3: deterministic tree-reduce of per-batch entropies -> mean scalar.
// ---------------------------------------------------------------------------
__global__ __launch_bounds__(256) void reduce_kernel(
    const float* __restrict__ ent_ws, float* __restrict__ out_scalar)
{
    __shared__ float sm[NB];
    const int t = threadIdx.x;
    sm[t] = ent_ws[t];
    __syncthreads();
    for (int s = NB / 2; s > 0; s >>= 1) {
        if (t < s) sm[t] += sm[t + s];
        __syncthreads();
    }
    if (t == 0) out_scalar[0] = sm[0] * (1.0f / NB);
}

extern "C" void kernel_launch(void* const* d_in, const int* in_sizes, int n_in,
                              void* d_out, int out_size, void* d_ws, size_t ws_size,
                              hipStream_t stream) {
    const int*   seq    = (const int*)  d_in[0];
    const float* embed  = (const float*)d_in[1];
    const float* w1     = (const float*)d_in[2];
    const float* b1     = (const float*)d_in[3];
    const float* w2     = (const float*)d_in[4];
    const float* b2     = (const float*)d_in[5];
    const float* ln_g   = (const float*)d_in[6];
    const float* ln_b   = (const float*)d_in[7];
    const float* gate_w = (const float*)d_in[8];
    const float* gate_b = (const float*)d_in[9];
    const float* q_w    = (const float*)d_in[10];
    const float* q_b    = (const float*)d_in[11];
    const float* out_w  = (const float*)d_in[12];
    const float* out_b  = (const float*)d_in[13];
    float* out = (float*)d_out;

    float* ws       = (float*)d_ws;
    float* wsG      = ws;                      // 4096 floats
    float* wsO      = ws + 4096;               // 4096 floats
    int*   wsOrder  = (int*)(ws + 8192);       // 64 ints
    float* entw     = ws + 8192 + 64;          // 256 floats

    precompute_kernel<<<1, 256, 0, stream>>>(embed, w1, b1, w2, b2, ln_g, ln_b,
                                             gate_w, gate_b, q_w, q_b, out_w,
                                             wsG, wsO, wsOrder);
    batch_kernel<<<NB, 256, 0, stream>>>(seq, out_b, wsG, wsO, wsOrder, entw, out);
    reduce_kernel<<<1, 256, 0, stream>>>(entw, out + (size_t)NB * VOC);
}

// Round 2
// 30.744 us; speedup vs baseline: 3.9091x; 3.9091x over previous
//
#include <hip/hip_runtime.h>

#define HID 64
#define VOC 64
#define NSLOT 8
#define NB 256
#define SEQL 2048

// ---------------------------------------------------------------------------
// Kernel 1: per-vocab precompute. One wave per vocab id v (8 blocks x 8 waves).
// Lane i of wave v holds element i of every per-row vector; cross-lane
// operands come via __shfl (register broadcast), weight reads are coalesced.
// Outputs: wsH[v][i] = LN(embed+FFN) row, wsQ[v][i] = h_v @ q_w + q_b,
//          wsScore[v] = h_v . gate_w + gate_b.
// ---------------------------------------------------------------------------
__global__ __launch_bounds__(512) void vocab_kernel(
    const float* __restrict__ embed, const float* __restrict__ w1, const float* __restrict__ b1,
    const float* __restrict__ w2, const float* __restrict__ b2,
    const float* __restrict__ ln_g, const float* __restrict__ ln_b,
    const float* __restrict__ gate_w, const float* __restrict__ gate_b,
    const float* __restrict__ q_w, const float* __restrict__ q_b,
    float* __restrict__ wsH, float* __restrict__ wsQ, float* __restrict__ wsScore)
{
    const int lane = threadIdx.x & 63;
    const int wave = threadIdx.x >> 6;
    const int v = blockIdx.x * 8 + wave;

    const float e = embed[v * HID + lane];

    // FFN layer 1: lane handles hidden units j=lane and j=lane+64.
    float fa = b1[lane], fb = b1[HID + lane];
#pragma unroll
    for (int i = 0; i < HID; ++i) {
        const float ei = __shfl(e, i);
        fa = fmaf(ei, w1[i * 2 * HID + lane], fa);
        fb = fmaf(ei, w1[i * 2 * HID + HID + lane], fb);
    }
    fa = fmaxf(fa, 0.0f);
    fb = fmaxf(fb, 0.0f);

    // FFN layer 2 + residual: lane holds z[i=lane].
    float z = e + b2[lane];
#pragma unroll
    for (int j = 0; j < HID; ++j)
        z = fmaf(__shfl(fa, j), w2[j * HID + lane], z);
#pragma unroll
    for (int j = 0; j < HID; ++j)
        z = fmaf(__shfl(fb, j), w2[(HID + j) * HID + lane], z);

    // LayerNorm via wave butterfly reductions.
    float s = z;
#pragma unroll
    for (int m = 32; m; m >>= 1) s += __shfl_xor(s, m);
    const float mu = s * (1.0f / HID);
    const float d = z - mu;
    float vs = d * d;
#pragma unroll
    for (int m = 32; m; m >>= 1) vs += __shfl_xor(vs, m);
    const float inv = 1.0f / sqrtf(vs * (1.0f / HID) + 1e-5f);
    const float h = d * inv * ln_g[lane] + ln_b[lane];
    wsH[v * HID + lane] = h;

    // Gate score (wave reduce).
    float sc = h * gate_w[lane];
#pragma unroll
    for (int m = 32; m; m >>= 1) sc += __shfl_xor(sc, m);
    if (lane == 0) wsScore[v] = sc + gate_b[0];

    // Query row: q[v][i=lane] = q_b[i] + sum_k h[k] * q_w[k][i].
    float q = q_b[lane];
#pragma unroll
    for (int k = 0; k < HID; ++k)
        q = fmaf(__shfl(h, k), q_w[k * HID + lane], q);
    wsQ[v * HID + lane] = q;
}

// ---------------------------------------------------------------------------
// Kernel 2: one block per batch row. Histogram -> greedy top-8 multiset ->
// attention logits from h/q (lane-parallel) -> entropy gate -> ctx -> logits.
// ---------------------------------------------------------------------------
__global__ __launch_bounds__(256) void batch_kernel(
    const int* __restrict__ seq,
    const float* __restrict__ out_w, const float* __restrict__ out_b,
    const float* __restrict__ wsH, const float* __restrict__ wsQ,
    const float* __restrict__ wsScore,
    float* __restrict__ ent_ws, float* __restrict__ out)
{
    __shared__ int hist[VOC];
    __shared__ float sscore[VOC];
    __shared__ float hlds[VOC * (HID + 1)];   // stride-65: conflict-free row reads
    __shared__ float sq[HID];
    __shared__ int sorder[VOC];
    __shared__ int svids[NSLOT];
    __shared__ float sla[NSLOT];
    __shared__ float seff[NSLOT];
    __shared__ int shvlast;

    const int t = threadIdx.x;
    const int b = blockIdx.x;

    if (t < VOC) { hist[t] = 0; sscore[t] = wsScore[t]; }
    if (t == 0) shvlast = seq[(size_t)b * SEQL + SEQL - 1];
    __syncthreads();

    // Histogram of the 2048 vocab ids (int4 vector loads, LDS atomics).
    const int4* row4 = (const int4*)(seq + (size_t)b * SEQL);
    for (int p = t; p < SEQL / 4; p += 256) {
        const int4 vv = row4[p];
        atomicAdd(&hist[vv.x], 1);
        atomicAdd(&hist[vv.y], 1);
        atomicAdd(&hist[vv.z], 1);
        atomicAdd(&hist[vv.w], 1);
    }
    // Stage h into padded LDS (coalesced from global).
    for (int p = t; p < VOC * HID; p += 256)
        hlds[(p >> 6) * (HID + 1) + (p & 63)] = wsH[p];
    __syncthreads();

    // Rank vocab ids by score desc (tie -> lower id), load q row of last token.
    if (t < VOC) {
        const float sv = sscore[t];
        int r = 0;
        for (int u = 0; u < VOC; ++u) {
            const float su = sscore[u];
            if (su > sv || (su == sv && u < t)) ++r;
        }
        sorder[r] = t;
        sq[t] = wsQ[shvlast * HID + t];
    }
    __syncthreads();

    // Greedy top-8 multiset by descending score with multiplicity.
    if (t == 0) {
        int r = NSLOT, n = 0, pos = 0;
        while (r > 0) {
            const int v = sorder[pos++];
            int c = hist[v];
            if (c > r) c = r;
            for (int k = 0; k < c; ++k) svids[n++] = v;
            r -= c;
        }
    }
    __syncthreads();

    // Attention logits: 8 lanes, one slot each (dot of h_vid with q_vlast).
    if (t < NSLOT) {
        const float* hr = &hlds[svids[t] * (HID + 1)];
        float acc = 0.0f;
#pragma unroll
        for (int i = 0; i < HID; ++i) acc = fmaf(hr[i], sq[i], acc);
        sla[t] = acc * 0.125f;   // 1/sqrt(64)
    }
    __syncthreads();

    // Softmax + entropy gate (tiny, serial on t==0).
    if (t == 0) {
        float m = -1e30f;
        for (int k = 0; k < NSLOT; ++k) m = fmaxf(m, sla[k]);
        float e[NSLOT], s = 0.0f;
        for (int k = 0; k < NSLOT; ++k) { e[k] = expf(sla[k] - m); s += e[k]; }
        const float invs = 1.0f / s;
        float ent = 0.0f;
        for (int k = 0; k < NSLOT; ++k) {
            const float a = e[k] * invs;
            ent -= a * logf(a + 1e-9f);
        }
        const float high = (ent > 1.5f) ? 1.0f : 0.0f;
        for (int k = 0; k < NSLOT; ++k)
            seff[k] = (1.0f - high) * (e[k] * invs) + high * (1.0f / NSLOT);
        ent_ws[b] = ent;
    }
    __syncthreads();

    // ctx[i] = sum_k eff_k * h_vid_k[i]  (lane i), then logits via shfl bcast.
    if (t < VOC) {
        float ctx = 0.0f;
#pragma unroll
        for (int k = 0; k < NSLOT; ++k)
            ctx = fmaf(seff[k], hlds[svids[k] * (HID + 1) + t], ctx);
        float acc = out_b[t];
#pragma unroll
        for (int i = 0; i < HID; ++i)
            acc = fmaf(__shfl(ctx, i), out_w[i * VOC + t], acc);
        out[(size_t)b * VOC + t] = acc;
    }
}

// ---------------------------------------------------------------------------
// Kernel 3: deterministic tree-reduce of per-batch entropies -> mean scalar.
// ---------------------------------------------------------------------------
__global__ __launch_bounds__(256) void reduce_kernel(
    const float* __restrict__ ent_ws, float* __restrict__ out_scalar)
{
    __shared__ float sm[NB];
    const int t = threadIdx.x;
    sm[t] = ent_ws[t];
    __syncthreads();
    for (int s = NB / 2; s > 0; s >>= 1) {
        if (t < s) sm[t] += sm[t + s];
        __syncthreads();
    }
    if (t == 0) out_scalar[0] = sm[0] * (1.0f / NB);
}

extern "C" void kernel_launch(void* const* d_in, const int* in_sizes, int n_in,
                              void* d_out, int out_size, void* d_ws, size_t ws_size,
                              hipStream_t stream) {
    const int*   seq    = (const int*)  d_in[0];
    const float* embed  = (const float*)d_in[1];
    const float* w1     = (const float*)d_in[2];
    const float* b1     = (const float*)d_in[3];
    const float* w2     = (const float*)d_in[4];
    const float* b2     = (const float*)d_in[5];
    const float* ln_g   = (const float*)d_in[6];
    const float* ln_b   = (const float*)d_in[7];
    const float* gate_w = (const float*)d_in[8];
    const float* gate_b = (const float*)d_in[9];
    const float* q_w    = (const float*)d_in[10];
    const float* q_b    = (const float*)d_in[11];
    const float* out_w  = (const float*)d_in[12];
    const float* out_b  = (const float*)d_in[13];
    float* out = (float*)d_out;

    float* ws      = (float*)d_ws;
    float* wsH     = ws;              // 4096 floats
    float* wsQ     = ws + 4096;       // 4096 floats
    float* wsScore = ws + 8192;       // 64 floats
    float* entw    = ws + 8256;       // 256 floats

    vocab_kernel<<<8, 512, 0, stream>>>(embed, w1, b1, w2, b2, ln_g, ln_b,
                                        gate_w, gate_b, q_w, q_b,
                                        wsH, wsQ, wsScore);
    batch_kernel<<<NB, 256, 0, stream>>>(seq, out_w, out_b, wsH, wsQ, wsScore,
                                         entw, out);
    reduce_kernel<<<1, 256, 0, stream>>>(entw, out + (size_t)NB * VOC);
}